// Round 1
// baseline (335.041 us; speedup 1.0000x reference)
//
#include <hip/hip_runtime.h>
#include <stdint.h>

#pragma clang fp contract(off)

#define BB 16
#define NN 25200
#define CCH 85
#define KTOP 512
#define NBKT 1024
#define CAP 4096

// ws layout (bytes):
//   conf : float [BB*NN]            @ 0        (1,612,800)
//   hist : uint  [BB*NBKT]          @ 1612800  (65,536)
//   cls  : uint8 [BB*NN]            @ 1678336  (403,200)

__global__ __launch_bounds__(256) void k_conf(const float* __restrict__ x,
                                              float* __restrict__ conf,
                                              uint8_t* __restrict__ clsout,
                                              unsigned* __restrict__ hist) {
    __shared__ float tile[128 * CCH];
    const int blk = blockIdx.x;
    const int tid = threadIdx.x;

    // coalesced stage: 128 rows * 85 floats = 2720 float4
    const float4* src = (const float4*)x + (size_t)blk * 2720;
    float4* dst = (float4*)tile;
    for (int i = tid; i < 2720; i += 256) dst[i] = src[i];
    __syncthreads();

    const int r = tid >> 1;         // local row 0..127
    const int half = tid & 1;       // class half
    const float* row = tile + r * CCH;
    const float obj = row[4];

    float best = -1.0f;
    int bi = 0;
    const float* cp = row + 5 + half * 40;
#pragma unroll 8
    for (int j = 0; j < 40; ++j) {
        float p = cp[j] * obj;      // rounded product, same as reference
        if (p > best) { best = p; bi = j; }
    }
    bi += half * 40;

    float ov = __shfl_xor(best, 1);
    int   oi = __shfl_xor(bi, 1);
    if (half == 0) {
        if (ov > best) { best = ov; bi = oi; }  // tie -> keep lower class idx (half0)
        const int gr = blk * 128 + r;
        const bool valid = (obj > 0.01f) && (best > 0.01f);
        conf[gr] = valid ? best : -1.0f;
        clsout[gr] = (uint8_t)bi;
        if (valid) {
            const int b = gr / NN;
            int bk = (int)(best * 1024.0f);
            if (bk > NBKT - 1) bk = NBKT - 1;
            atomicAdd(&hist[b * NBKT + bk], 1u);
        }
    }
}

__global__ __launch_bounds__(1024) void k_main(const float* __restrict__ x,
                                               const float* __restrict__ target,
                                               const float* __restrict__ conf,
                                               const uint8_t* __restrict__ clsw,
                                               const unsigned* __restrict__ hist,
                                               float* __restrict__ out) {
    __shared__ union {
        unsigned long long cand[CAP];      // 32 KB (sort buffer)
        unsigned mask[KTOP][16];           // 32 KB (NMS suppression bitmask)
    } u;
    __shared__ float bx1[KTOP], by1[KTOP], bx2[KTOP], by2[KTOP];   // plain boxes
    __shared__ float ox1[KTOP], oy1[KTOP], ox2[KTOP], oy2[KTOP];   // class-offset boxes
    __shared__ float sarea[KTOP], sscore[KTOP];
    __shared__ int scls[KTOP];
    __shared__ unsigned sbuf[NBKT];
    __shared__ unsigned keepw[16];
    __shared__ unsigned long long wred[16];
    __shared__ int sh_tstar, sh_cnt;

    const int b = blockIdx.x;
    const int tid = threadIdx.x;

    // ---- A: histogram suffix-scan -> threshold bucket ----
    sbuf[tid] = hist[b * NBKT + tid];
    if (tid == 0) { sh_tstar = 0; sh_cnt = 0; }
    __syncthreads();
    for (int off = 1; off < NBKT; off <<= 1) {
        unsigned v = sbuf[tid];
        if (tid + off < NBKT) v += sbuf[tid + off];
        __syncthreads();
        sbuf[tid] = v;
        __syncthreads();
    }
    if (sbuf[tid] >= KTOP && (tid == NBKT - 1 || sbuf[tid + 1] < KTOP)) sh_tstar = tid;
    __syncthreads();
    const int tstar = sh_tstar;

    // ---- B: gather candidates (bucket >= tstar) as sortable keys ----
    const float* cb = conf + (size_t)b * NN;
    for (int i = tid; i < NN; i += 1024) {
        float c = cb[i];
        if (c > 0.0f) {
            int bk = (int)(c * 1024.0f);
            if (bk > NBKT - 1) bk = NBKT - 1;
            if (bk >= tstar) {
                int pos = atomicAdd(&sh_cnt, 1);
                if (pos < CAP) {
                    unsigned bits = __float_as_uint(c);
                    u.cand[pos] = ((unsigned long long)bits << 32) | (unsigned)(~i);
                }
            }
        }
    }
    __syncthreads();
    const int M = min(sh_cnt, CAP);
    int n2 = KTOP;
    while (n2 < M) n2 <<= 1;
    for (int i = M + tid; i < n2; i += 1024) u.cand[i] = 0ull;
    __syncthreads();

    // ---- C: bitonic sort descending ----
    for (int kk = 2; kk <= n2; kk <<= 1) {
        for (int j = kk >> 1; j > 0; j >>= 1) {
            for (int i = tid; i < n2; i += 1024) {
                int ixj = i ^ j;
                if (ixj > i) {
                    unsigned long long a = u.cand[i], c2 = u.cand[ixj];
                    bool asc = (i & kk) != 0;
                    bool sw = asc ? (a > c2) : (a < c2);
                    if (sw) { u.cand[i] = c2; u.cand[ixj] = a; }
                }
            }
            __syncthreads();
        }
    }

    // ---- D: extract top-512, load rows, build boxes ----
    const float tb0 = target[0], tb1 = target[1], tb2 = target[2], tb3 = target[3];
    const int tcls = (int)target[5];
    unsigned long long mykey = (tid < KTOP) ? u.cand[tid] : 0ull;
    __syncthreads();   // done reading cand; union may be overwritten below
    if (tid < KTOP) {
        float sc = __uint_as_float((unsigned)(mykey >> 32));
        unsigned idx = ~((unsigned)mykey);
        bool v = sc > 0.0f;
        sscore[tid] = sc;
        float X1 = 0.f, Y1 = 0.f, X2 = 0.f, Y2 = 0.f;
        int cl = 0;
        if (v) {
            const float* rw = x + ((size_t)b * NN + idx) * CCH;
            float cx = rw[0], cy = rw[1];
            float w = rw[2] * 0.5f, h = rw[3] * 0.5f;
            X1 = cx - w; Y1 = cy - h; X2 = cx + w; Y2 = cy + h;
            cl = clsw[(size_t)b * NN + idx];
        }
        bx1[tid] = X1; by1[tid] = Y1; bx2[tid] = X2; by2[tid] = Y2;
        float offv = (float)cl * 4096.0f;
        float o1 = X1 + offv, o2 = Y1 + offv, o3 = X2 + offv, o4 = Y2 + offv;
        ox1[tid] = o1; oy1[tid] = o2; ox2[tid] = o3; oy2[tid] = o4;
        sarea[tid] = (o3 - o1) * (o4 - o2);
        scls[tid] = cl;
    }
    __syncthreads();

    // ---- E: 512x512 suppression bitmask (bit j of mask[i][w]: i suppresses j>i) ----
    for (int p = tid; p < KTOP * 16; p += 1024) {
        int i = p & (KTOP - 1);
        int w = p >> 9;
        float ax1 = ox1[i], ay1 = oy1[i], ax2 = ox2[i], ay2 = oy2[i], aa = sarea[i];
        unsigned bits = 0u;
        for (int jj = 0; jj < 32; ++jj) {
            int j = (w << 5) + jj;
            if (j > i) {
                float lx = fmaxf(ax1, ox1[j]);
                float ly = fmaxf(ay1, oy1[j]);
                float rx = fminf(ax2, ox2[j]);
                float ry = fminf(ay2, oy2[j]);
                float iw = fmaxf(rx - lx, 0.0f);
                float ih = fmaxf(ry - ly, 0.0f);
                float inter = iw * ih;
                float den = aa + sarea[j] - inter + 1e-9f;
                float iou = inter / den;
                if (iou > 0.5f) bits |= (1u << jj);
            }
        }
        u.mask[i][w] = bits;
    }
    __syncthreads();

    // ---- F: sequential greedy scan (wave 0, lockstep, no barriers) ----
    if (tid < 64) {
        unsigned sup = 0u, kp = 0u;
        for (int i = 0; i < KTOP; ++i) {
            int wi = i >> 5;
            unsigned sw = __shfl(sup, wi);
            bool suppressed = (sw >> (i & 31)) & 1u;
            bool vi = sscore[i] > 0.0f;
            if (vi && !suppressed) {           // wave-uniform condition
                if (tid < 16) sup |= u.mask[i][tid];
                if (tid == wi) kp |= (1u << (i & 31));
            }
        }
        if (tid < 16) keepw[tid] = kp;
    }
    __syncthreads();

    // ---- G: masked argmax of IoU-with-target, output ----
    float m = -1.0f;
    if (tid < KTOP) {
        bool kept = (keepw[tid >> 5] >> (tid & 31)) & 1u;
        if (kept && scls[tid] == tcls) {
            float lx = fmaxf(bx1[tid], tb0);
            float ly = fmaxf(by1[tid], tb1);
            float rx = fminf(bx2[tid], tb2);
            float ry = fminf(by2[tid], tb3);
            float iw = fmaxf(rx - lx, 0.0f);
            float ih = fmaxf(ry - ly, 0.0f);
            float inter = iw * ih;
            float areab = (bx2[tid] - bx1[tid]) * (by2[tid] - by1[tid]);
            float areat = (tb2 - tb0) * (tb3 - tb1);
            float den = areab + areat - inter + 1e-9f;
            m = inter / den;
        }
    }
    unsigned mb = __float_as_uint(m);
    unsigned mono = (mb & 0x80000000u) ? ~mb : (mb | 0x80000000u);
    unsigned long long key = ((unsigned long long)mono << 32) | (unsigned)(~tid);
    for (int d = 32; d > 0; d >>= 1) {
        unsigned long long o = __shfl_xor(key, d);
        if (o > key) key = o;
    }
    if ((tid & 63) == 0) wred[tid >> 6] = key;
    __syncthreads();
    if (tid == 0) {
        unsigned long long bestk = wred[0];
        for (int i = 1; i < 16; ++i)
            if (wred[i] > bestk) bestk = wred[i];
        unsigned mono2 = (unsigned)(bestk >> 32);
        unsigned mbits = (mono2 & 0x80000000u) ? (mono2 & 0x7FFFFFFFu) : ~mono2;
        float mstar = __uint_as_float(mbits);
        int j = (int)(~((unsigned)bestk));
        out[b] = (mstar >= 0.0f) ? sscore[j] * mstar : 0.0f;
    }
}

extern "C" void kernel_launch(void* const* d_in, const int* in_sizes, int n_in,
                              void* d_out, int out_size, void* d_ws, size_t ws_size,
                              hipStream_t stream) {
    const float* x = (const float*)d_in[0];
    const float* target = (const float*)d_in[1];
    float* out = (float*)d_out;

    char* ws = (char*)d_ws;
    float* conf = (float*)ws;
    unsigned* hist = (unsigned*)(ws + 1612800);
    uint8_t* clsw = (uint8_t*)(ws + 1612800 + 65536);

    hipMemsetAsync(hist, 0, BB * NBKT * sizeof(unsigned), stream);
    k_conf<<<dim3((BB * NN) / 128), dim3(256), 0, stream>>>(x, conf, clsw, hist);
    k_main<<<dim3(BB), dim3(1024), 0, stream>>>(x, target, conf, clsw, hist, out);
}

// Round 2
// 325.897 us; speedup vs baseline: 1.0281x; 1.0281x over previous
//
#include <hip/hip_runtime.h>
#include <stdint.h>

#pragma clang fp contract(off)

#define BB 16
#define NN 25200
#define CCH 85
#define KTOP 512
#define NBKT 1024
#define CAP 1024

// ws layout (bytes):
//   conf : float [BB*NN]            @ 0        (1,612,800)
//   hist : uint  [BB*NBKT]          @ 1612800  (65,536)
//   cls  : uint8 [BB*NN]            @ 1678336  (403,200)

__global__ __launch_bounds__(256) void k_conf(const float* __restrict__ x,
                                              float* __restrict__ conf,
                                              uint8_t* __restrict__ clsout,
                                              unsigned* __restrict__ hist) {
    __shared__ float tile[128 * CCH];
    const int blk = blockIdx.x;
    const int tid = threadIdx.x;

    const float4* src = (const float4*)x + (size_t)blk * 2720;
    float4* dst = (float4*)tile;
    for (int i = tid; i < 2720; i += 256) dst[i] = src[i];
    __syncthreads();

    const int r = tid >> 1;
    const int half = tid & 1;
    const float* row = tile + r * CCH;
    const float obj = row[4];

    float best = -1.0f;
    int bi = 0;
    const float* cp = row + 5 + half * 40;
#pragma unroll 8
    for (int j = 0; j < 40; ++j) {
        float p = cp[j] * obj;
        if (p > best) { best = p; bi = j; }
    }
    bi += half * 40;

    float ov = __shfl_xor(best, 1);
    int   oi = __shfl_xor(bi, 1);
    if (half == 0) {
        if (ov > best) { best = ov; bi = oi; }
        const int gr = blk * 128 + r;
        const bool valid = (obj > 0.01f) && (best > 0.01f);
        conf[gr] = valid ? best : -1.0f;
        clsout[gr] = (uint8_t)bi;
        if (valid) {
            const int b = gr / NN;
            int bk = (int)(best * 1024.0f);
            if (bk > NBKT - 1) bk = NBKT - 1;
            atomicAdd(&hist[b * NBKT + bk], 1u);
        }
    }
}

__global__ __launch_bounds__(1024) void k_main(const float* __restrict__ x,
                                               const float* __restrict__ target,
                                               const float* __restrict__ conf,
                                               const uint8_t* __restrict__ clsw,
                                               const unsigned* __restrict__ hist,
                                               float* __restrict__ out) {
    __shared__ union {
        unsigned long long cand[CAP];      // 8 KB sort/exchange buffer
        unsigned maskT[KTOP][16];          // 32 KB: bit j of [i][w]: j<i suppresses i
    } u;
    __shared__ float4 ox4[KTOP];           // offset boxes (AoS for broadcast b128)
    __shared__ float4 bb4[KTOP];           // plain boxes
    __shared__ float sscore[KTOP];
    __shared__ int scls[KTOP];
    __shared__ unsigned sbuf[NBKT];
    __shared__ unsigned keep_words[16];
    __shared__ unsigned long long wred[16];
    __shared__ int sh_tstar, sh_cnt;

    const int b = blockIdx.x;
    const int tid = threadIdx.x;
    const int lane = tid & 63;

    // ---- A: histogram suffix-scan -> threshold bucket ----
    sbuf[tid] = hist[b * NBKT + tid];
    if (tid == 0) { sh_tstar = 0; sh_cnt = 0; }
    __syncthreads();
    for (int off = 1; off < NBKT; off <<= 1) {
        unsigned v = sbuf[tid];
        if (tid + off < NBKT) v += sbuf[tid + off];
        __syncthreads();
        sbuf[tid] = v;
        __syncthreads();
    }
    if (sbuf[tid] >= KTOP && (tid == NBKT - 1 || sbuf[tid + 1] < KTOP)) sh_tstar = tid;
    __syncthreads();
    const int tstar = sh_tstar;

    // ---- B: gather candidates (bucket >= tstar); wave-aggregated append ----
    const float* cb = conf + (size_t)b * NN;
    for (int i = tid; i < NN; i += 1024) {
        float c = cb[i];
        bool want = false;
        if (c > 0.0f) {
            int bk = (int)(c * 1024.0f);
            if (bk > NBKT - 1) bk = NBKT - 1;
            want = (bk >= tstar);
        }
        unsigned long long bal = __ballot(want);
        int base = 0;
        if (lane == 0 && bal) base = atomicAdd(&sh_cnt, __popcll(bal));
        base = __shfl(base, 0);
        if (want) {
            int pos = base + __popcll(bal & ((1ull << lane) - 1ull));
            if (pos < CAP) {
                unsigned bits = __float_as_uint(c);
                u.cand[pos] = ((unsigned long long)bits << 32) | (unsigned)(~i);
            }
        }
    }
    __syncthreads();
    const int M = min(sh_cnt, CAP);

    // ---- C: hybrid bitonic sort, descending; 1 key per thread in register ----
    unsigned long long key = (tid < M) ? u.cand[tid] : 0ull;
    __syncthreads();
    for (int kk = 2; kk <= CAP; kk <<= 1) {
        for (int j = kk >> 1; j > 0; j >>= 1) {
            unsigned long long partner;
            if (j >= 64) {
                u.cand[tid] = key;
                __syncthreads();
                partner = u.cand[tid ^ j];
                __syncthreads();
            } else {
                partner = __shfl_xor(key, j);
            }
            bool desc = (tid & kk) == 0;
            bool lower = (tid & j) == 0;
            bool take_max = (lower == desc);
            bool pg = partner > key;
            key = (take_max == pg) ? partner : key;
        }
    }

    // ---- D: extract top-512, load rows, build boxes ----
    const float tb0 = target[0], tb1 = target[1], tb2 = target[2], tb3 = target[3];
    const int tcls = (int)target[5];
    if (tid < KTOP) {
        float sc = __uint_as_float((unsigned)(key >> 32));
        unsigned idx = ~((unsigned)key);
        bool v = sc > 0.0f;
        sscore[tid] = sc;
        float X1 = 0.f, Y1 = 0.f, X2 = 0.f, Y2 = 0.f;
        int cl = 0;
        if (v) {
            const float* rw = x + ((size_t)b * NN + idx) * CCH;
            float cx = rw[0], cy = rw[1];
            float w = rw[2] * 0.5f, h = rw[3] * 0.5f;
            X1 = cx - w; Y1 = cy - h; X2 = cx + w; Y2 = cy + h;
            cl = clsw[(size_t)b * NN + idx];
        }
        bb4[tid] = make_float4(X1, Y1, X2, Y2);
        float offv = (float)cl * 4096.0f;
        ox4[tid] = make_float4(X1 + offv, Y1 + offv, X2 + offv, Y2 + offv);
        scls[tid] = cl;
    }
    __syncthreads();

    // ---- E: transposed suppression mask (lower triangle only) ----
    for (int p = tid; p < KTOP * 16; p += 1024) {
        int i = p & (KTOP - 1);
        int w = p >> 9;
        unsigned bits = 0u;
        if ((w << 5) < i) {
            float4 bi = ox4[i];
            float ai = (bi.z - bi.x) * (bi.w - bi.y);
            int jbase = w << 5;
            for (int jj = 0; jj < 32; ++jj) {
                int j = jbase + jj;
                float4 bj = ox4[j];            // broadcast b128
                float lx = fmaxf(bi.x, bj.x);
                float ly = fmaxf(bi.y, bj.y);
                float rx = fminf(bi.z, bj.z);
                float ry = fminf(bi.w, bj.w);
                float inter = fmaxf(rx - lx, 0.0f) * fmaxf(ry - ly, 0.0f);
                float aj = (bj.z - bj.x) * (bj.w - bj.y);
                float den = ai + aj - inter + 1e-9f;
                float iou = inter / den;
                unsigned hit = (unsigned)((j < i) & (iou > 0.5f));
                bits |= hit << jj;
            }
        }
        u.maskT[i][w] = bits;
    }
    __syncthreads();

    // ---- F: greedy scan, wave 0; mask-row prefetch keeps loads off the chain ----
    if (tid < 64) {
        const int l15 = lane & 15;
        unsigned keepw = 0u;
        unsigned r_cur = u.maskT[0][l15];
        float sc_cur = sscore[0];
        for (int i = 0; i < KTOP; ++i) {
            unsigned r_next = 0u; float sc_next = 0.f;
            if (i < KTOP - 1) { r_next = u.maskT[i + 1][l15]; sc_next = sscore[i + 1]; }
            unsigned long long bal = __ballot((r_cur & keepw) != 0u);
            bool sup = (bal & 0xFFFFull) != 0ull;
            bool kept = (sc_cur > 0.0f) && !sup;
            if (kept && lane == (i >> 5)) keepw |= (1u << (i & 31));
            r_cur = r_next; sc_cur = sc_next;
        }
        if (lane < 16) keep_words[lane] = keepw;
    }
    __syncthreads();

    // ---- G: masked argmax of IoU-with-target, output ----
    float m = -1.0f;
    if (tid < KTOP) {
        bool kept = (keep_words[tid >> 5] >> (tid & 31)) & 1u;
        if (kept && scls[tid] == tcls) {
            float4 bx = bb4[tid];
            float lx = fmaxf(bx.x, tb0);
            float ly = fmaxf(bx.y, tb1);
            float rx = fminf(bx.z, tb2);
            float ry = fminf(bx.w, tb3);
            float inter = fmaxf(rx - lx, 0.0f) * fmaxf(ry - ly, 0.0f);
            float areab = (bx.z - bx.x) * (bx.w - bx.y);
            float areat = (tb2 - tb0) * (tb3 - tb1);
            float den = areab + areat - inter + 1e-9f;
            m = inter / den;
        }
    }
    unsigned mb = __float_as_uint(m);
    unsigned mono = (mb & 0x80000000u) ? ~mb : (mb | 0x80000000u);
    unsigned long long rk = ((unsigned long long)mono << 32) | (unsigned)(~tid);
    for (int d = 32; d > 0; d >>= 1) {
        unsigned long long o = __shfl_xor(rk, d);
        if (o > rk) rk = o;
    }
    if ((tid & 63) == 0) wred[tid >> 6] = rk;
    __syncthreads();
    if (tid == 0) {
        unsigned long long bestk = wred[0];
        for (int i = 1; i < 16; ++i)
            if (wred[i] > bestk) bestk = wred[i];
        unsigned mono2 = (unsigned)(bestk >> 32);
        unsigned mbits = (mono2 & 0x80000000u) ? (mono2 & 0x7FFFFFFFu) : ~mono2;
        float mstar = __uint_as_float(mbits);
        int j = (int)(~((unsigned)bestk));
        out[b] = (mstar >= 0.0f) ? sscore[j] * mstar : 0.0f;
    }
}

extern "C" void kernel_launch(void* const* d_in, const int* in_sizes, int n_in,
                              void* d_out, int out_size, void* d_ws, size_t ws_size,
                              hipStream_t stream) {
    const float* x = (const float*)d_in[0];
    const float* target = (const float*)d_in[1];
    float* out = (float*)d_out;

    char* ws = (char*)d_ws;
    float* conf = (float*)ws;
    unsigned* hist = (unsigned*)(ws + 1612800);
    uint8_t* clsw = (uint8_t*)(ws + 1612800 + 65536);

    hipMemsetAsync(hist, 0, BB * NBKT * sizeof(unsigned), stream);
    k_conf<<<dim3((BB * NN) / 128), dim3(256), 0, stream>>>(x, conf, clsw, hist);
    k_main<<<dim3(BB), dim3(1024), 0, stream>>>(x, target, conf, clsw, hist, out);
}

// Round 3
// 283.310 us; speedup vs baseline: 1.1826x; 1.1503x over previous
//
#include <hip/hip_runtime.h>
#include <stdint.h>

#pragma clang fp contract(off)

#define BB 16
#define NN 25200
#define CCH 85
#define KTOP 512
#define NBKT 1024
#define CAP 1024

// ws layout (bytes):
//   conf : float [BB*NN] @ 0  (1,612,800)  -- per-batch region b*100800, reused
//          after k_sel's block b is done with it:
//            +0      bb4[512]  float4   (8192)
//            +8192   ox4[512]  float4   (8192)
//            +16384  score[512] float   (2048)
//            +18432  cls[512]  int      (2048)
//            +32768  maskT[512][16] u32 (32768)   (ends 65536 < 100800)
//   clsw : uint8 [BB*NN] @ 1612800 (403,200)

__global__ __launch_bounds__(256) void k_conf(const float* __restrict__ x,
                                              float* __restrict__ conf,
                                              uint8_t* __restrict__ clsout) {
    __shared__ float tile[128 * CCH];
    const int blk = blockIdx.x;
    const int tid = threadIdx.x;

    const float4* src = (const float4*)x + (size_t)blk * 2720;
    float4* dst = (float4*)tile;
    for (int i = tid; i < 2720; i += 256) dst[i] = src[i];
    __syncthreads();

    const int r = tid >> 1;
    const int half = tid & 1;
    const float* row = tile + r * CCH;
    const float obj = row[4];

    float best = -1.0f;
    int bi = 0;
    const float* cp = row + 5 + half * 40;
#pragma unroll 8
    for (int j = 0; j < 40; ++j) {
        float p = cp[j] * obj;
        if (p > best) { best = p; bi = j; }
    }
    bi += half * 40;

    float ov = __shfl_xor(best, 1);
    int   oi = __shfl_xor(bi, 1);
    if (half == 0) {
        if (ov > best) { best = ov; bi = oi; }   // tie -> lower class idx
        const int gr = blk * 128 + r;
        const bool valid = (obj > 0.01f) && (best > 0.01f);
        conf[gr] = valid ? best : -1.0f;
        clsout[gr] = (uint8_t)bi;
    }
}

__global__ __launch_bounds__(1024) void k_sel(const float* __restrict__ x,
                                              const uint8_t* __restrict__ clsw,
                                              char* __restrict__ ws) {
    __shared__ unsigned hist[NBKT];
    __shared__ unsigned long long cand[CAP];
    __shared__ int sh_tstar, sh_cnt;

    const int b = blockIdx.x;
    const int tid = threadIdx.x;
    const int lane = tid & 63;
    const float* cb = (const float*)ws + (size_t)b * NN;

    // ---- A: per-batch histogram in LDS ----
    hist[tid] = 0u;
    if (tid == 0) { sh_tstar = 0; sh_cnt = 0; }
    __syncthreads();
    for (int i = tid; i < NN; i += 1024) {
        float c = cb[i];
        if (c > 0.0f) {
            int bk = (int)(c * 1024.0f);
            if (bk > NBKT - 1) bk = NBKT - 1;
            atomicAdd(&hist[bk], 1u);
        }
    }
    __syncthreads();

    // ---- suffix-scan -> threshold bucket ----
    for (int off = 1; off < NBKT; off <<= 1) {
        unsigned v = hist[tid];
        if (tid + off < NBKT) v += hist[tid + off];
        __syncthreads();
        hist[tid] = v;
        __syncthreads();
    }
    if (hist[tid] >= KTOP && (tid == NBKT - 1 || hist[tid + 1] < KTOP)) sh_tstar = tid;
    __syncthreads();
    const int tstar = sh_tstar;

    // ---- B: gather candidates (bucket >= tstar); wave-aggregated append ----
    for (int i = tid; i < NN; i += 1024) {
        float c = cb[i];
        bool want = false;
        if (c > 0.0f) {
            int bk = (int)(c * 1024.0f);
            if (bk > NBKT - 1) bk = NBKT - 1;
            want = (bk >= tstar);
        }
        unsigned long long bal = __ballot(want);
        int base = 0;
        if (lane == 0 && bal) base = atomicAdd(&sh_cnt, __popcll(bal));
        base = __shfl(base, 0);
        if (want) {
            int pos = base + __popcll(bal & ((1ull << lane) - 1ull));
            if (pos < CAP) {
                unsigned bits = __float_as_uint(c);
                cand[pos] = ((unsigned long long)bits << 32) | (unsigned)(~i);
            }
        }
    }
    __syncthreads();
    const int M = min(sh_cnt, CAP);

    // ---- C: hybrid bitonic sort, descending; 1 key/thread in register ----
    unsigned long long key = (tid < M) ? cand[tid] : 0ull;
    __syncthreads();
    for (int kk = 2; kk <= CAP; kk <<= 1) {
        for (int j = kk >> 1; j > 0; j >>= 1) {
            unsigned long long partner;
            if (j >= 64) {
                cand[tid] = key;
                __syncthreads();
                partner = cand[tid ^ j];
                __syncthreads();
            } else {
                partner = __shfl_xor(key, j);
            }
            bool desc = (tid & kk) == 0;
            bool lower = (tid & j) == 0;
            bool take_max = (lower == desc);
            bool pg = partner > key;
            key = (take_max == pg) ? partner : key;
        }
    }

    // ---- D: top-512 -> boxes/scores/cls into per-batch ws region ----
    char* base_b = ws + (size_t)b * 100800;
    if (tid < KTOP) {
        float sc = __uint_as_float((unsigned)(key >> 32));
        unsigned idx = ~((unsigned)key);
        bool v = sc > 0.0f;
        float X1 = 0.f, Y1 = 0.f, X2 = 0.f, Y2 = 0.f;
        int cl = 0;
        if (v) {
            const float* rw = x + ((size_t)b * NN + idx) * CCH;
            float cx = rw[0], cy = rw[1];
            float w = rw[2] * 0.5f, h = rw[3] * 0.5f;
            X1 = cx - w; Y1 = cy - h; X2 = cx + w; Y2 = cy + h;
            cl = clsw[(size_t)b * NN + idx];
        }
        float offv = (float)cl * 4096.0f;
        ((float4*)(base_b))[tid] = make_float4(X1, Y1, X2, Y2);
        ((float4*)(base_b + 8192))[tid] = make_float4(X1 + offv, Y1 + offv, X2 + offv, Y2 + offv);
        ((float*)(base_b + 16384))[tid] = sc;
        ((int*)(base_b + 18432))[tid] = cl;
    }
}

__global__ __launch_bounds__(1024) void k_mask(char* __restrict__ ws) {
    __shared__ float4 sox[KTOP];
    const int slice = blockIdx.x;     // 0..7
    const int b = blockIdx.y;         // 0..15
    const int tid = threadIdx.x;
    char* base_b = ws + (size_t)b * 100800;

    if (tid < KTOP) sox[tid] = ((const float4*)(base_b + 8192))[tid];
    __syncthreads();

    const int i = slice * 64 + (tid >> 4);
    const int w = tid & 15;
    unsigned bits = 0u;
    if ((w << 5) < i) {
        float4 bi = sox[i];
        float ai = (bi.z - bi.x) * (bi.w - bi.y);
        const int jbase = w << 5;
        for (int jj = 0; jj < 32; ++jj) {
            int j = jbase + jj;
            float4 bj = sox[j];
            float lx = fmaxf(bi.x, bj.x);
            float ly = fmaxf(bi.y, bj.y);
            float rx = fminf(bi.z, bj.z);
            float ry = fminf(bi.w, bj.w);
            float inter = fmaxf(rx - lx, 0.0f) * fmaxf(ry - ly, 0.0f);
            float aj = (bj.z - bj.x) * (bj.w - bj.y);
            float den = ai + aj - inter + 1e-9f;
            float iou = inter / den;
            unsigned hit = (unsigned)((j < i) & (iou > 0.5f));
            bits |= hit << jj;
        }
    }
    ((unsigned*)(base_b + 32768))[slice * 1024 + tid] = bits;
}

__global__ __launch_bounds__(512) void k_nms(const float* __restrict__ target,
                                             const char* __restrict__ ws,
                                             float* __restrict__ out) {
    __shared__ unsigned smask[KTOP][16];     // 32 KB
    __shared__ float4 sbb[KTOP];             // 8 KB
    __shared__ float sscore[KTOP];
    __shared__ int scls[KTOP];
    __shared__ unsigned keep_words[16];
    __shared__ unsigned long long wred[8];

    const int b = blockIdx.x;
    const int tid = threadIdx.x;
    const char* base_b = ws + (size_t)b * 100800;

    // stage everything into LDS (coalesced)
    const uint4* mg = (const uint4*)(base_b + 32768);
    for (int p = tid; p < 2048; p += 512) ((uint4*)smask)[p] = mg[p];
    sbb[tid] = ((const float4*)(base_b))[tid];
    sscore[tid] = ((const float*)(base_b + 16384))[tid];
    scls[tid] = ((const int*)(base_b + 18432))[tid];
    __syncthreads();

    // ---- F: greedy scan on wave 0, mask-row prefetched ----
    if (tid < 64) {
        const int l15 = tid & 15;
        unsigned keepw = 0u;
        unsigned r_cur = smask[0][l15];
        float sc_cur = sscore[0];
        for (int i = 0; i < KTOP; ++i) {
            unsigned r_next = 0u; float sc_next = 0.f;
            if (i < KTOP - 1) { r_next = smask[i + 1][l15]; sc_next = sscore[i + 1]; }
            unsigned long long bal = __ballot((r_cur & keepw) != 0u);
            bool sup = (bal & 0xFFFFull) != 0ull;
            bool kept = (sc_cur > 0.0f) && !sup;
            if (kept && tid == (i >> 5)) keepw |= (1u << (i & 31));
            r_cur = r_next; sc_cur = sc_next;
        }
        if (tid < 16) keep_words[tid] = keepw;
    }
    __syncthreads();

    // ---- G: masked argmax of IoU-with-target, output ----
    const float tb0 = target[0], tb1 = target[1], tb2 = target[2], tb3 = target[3];
    const int tcls = (int)target[5];
    float m = -1.0f;
    {
        bool kept = (keep_words[tid >> 5] >> (tid & 31)) & 1u;
        if (kept && scls[tid] == tcls) {
            float4 bx = sbb[tid];
            float lx = fmaxf(bx.x, tb0);
            float ly = fmaxf(bx.y, tb1);
            float rx = fminf(bx.z, tb2);
            float ry = fminf(bx.w, tb3);
            float inter = fmaxf(rx - lx, 0.0f) * fmaxf(ry - ly, 0.0f);
            float areab = (bx.z - bx.x) * (bx.w - bx.y);
            float areat = (tb2 - tb0) * (tb3 - tb1);
            float den = areab + areat - inter + 1e-9f;
            m = inter / den;
        }
    }
    unsigned mb = __float_as_uint(m);
    unsigned mono = (mb & 0x80000000u) ? ~mb : (mb | 0x80000000u);
    unsigned long long rk = ((unsigned long long)mono << 32) | (unsigned)(~tid);
    for (int d = 32; d > 0; d >>= 1) {
        unsigned long long o = __shfl_xor(rk, d);
        if (o > rk) rk = o;
    }
    if ((tid & 63) == 0) wred[tid >> 6] = rk;
    __syncthreads();
    if (tid == 0) {
        unsigned long long bestk = wred[0];
        for (int i = 1; i < 8; ++i)
            if (wred[i] > bestk) bestk = wred[i];
        unsigned mono2 = (unsigned)(bestk >> 32);
        unsigned mbits = (mono2 & 0x80000000u) ? (mono2 & 0x7FFFFFFFu) : ~mono2;
        float mstar = __uint_as_float(mbits);
        int j = (int)(~((unsigned)bestk));
        out[b] = (mstar >= 0.0f) ? sscore[j] * mstar : 0.0f;
    }
}

extern "C" void kernel_launch(void* const* d_in, const int* in_sizes, int n_in,
                              void* d_out, int out_size, void* d_ws, size_t ws_size,
                              hipStream_t stream) {
    const float* x = (const float*)d_in[0];
    const float* target = (const float*)d_in[1];
    float* out = (float*)d_out;

    char* ws = (char*)d_ws;
    float* conf = (float*)ws;
    uint8_t* clsw = (uint8_t*)(ws + 1612800);

    k_conf<<<dim3((BB * NN) / 128), dim3(256), 0, stream>>>(x, conf, clsw);
    k_sel<<<dim3(BB), dim3(1024), 0, stream>>>(x, clsw, ws);
    k_mask<<<dim3(8, BB), dim3(1024), 0, stream>>>(ws);
    k_nms<<<dim3(BB), dim3(512), 0, stream>>>(target, ws, out);
}